// Round 5
// baseline (23.909 us; speedup 1.0000x reference)
//
#include <hip/hip_runtime.h>
#include <math.h>

#define H_DIM 1024
#define N_DIM 64
#define L_DIM 2048
#define CHUNK 4
#define NT 512   // NT * CHUNK == L_DIM ; 8 waves/block, 4 blocks/CU -> 32 waves/CU

typedef float f32x2 __attribute__((ext_vector_type(2)));
typedef float f32x4 __attribute__((ext_vector_type(4)));

// HW transcendentals: v_sin/v_cos take REVOLUTIONS, v_exp_f32 is 2^x,
// v_fract_f32 is x - floor(x).
__device__ __forceinline__ float exp2_hw(float x) {
    float o; asm("v_exp_f32 %0, %1" : "=v"(o) : "v"(x)); return o;
}
__device__ __forceinline__ float sin_rev(float x) {
    float o; asm("v_sin_f32 %0, %1" : "=v"(o) : "v"(x)); return o;
}
__device__ __forceinline__ float cos_rev(float x) {
    float o; asm("v_cos_f32 %0, %1" : "=v"(o) : "v"(x)); return o;
}
__device__ __forceinline__ float fract_hw(float x) {
    float o; asm("v_fract_f32 %0, %1" : "=v"(o) : "v"(x)); return o;
}
__device__ __forceinline__ f32x2 pk_add(f32x2 a, f32x2 b) {
    f32x2 d; asm("v_pk_add_f32 %0, %1, %2" : "=v"(d) : "v"(a), "v"(b)); return d;
}
// d = WI * broadcast(mcms.hi)   (ms to both lanes via op_sel)
__device__ __forceinline__ f32x2 pk_mul_bhi(f32x2 wi, f32x2 mcms) {
    f32x2 d;
    asm("v_pk_mul_f32 %0, %1, %2 op_sel:[0,1] op_sel_hi:[1,1]"
        : "=v"(d) : "v"(wi), "v"(mcms));
    return d;
}
// d = WR * broadcast(mcms.lo) - t   (mc to both lanes, fused subtract)
__device__ __forceinline__ f32x2 pk_fms_blo(f32x2 wr, f32x2 mcms, f32x2 t) {
    f32x2 d;
    asm("v_pk_fma_f32 %0, %1, %2, %3 op_sel:[0,0,0] op_sel_hi:[1,0,1] neg_lo:[0,0,1] neg_hi:[0,0,1]"
        : "=v"(d) : "v"(wr), "v"(mcms), "v"(t));
    return d;
}

// Block h (512 threads): thread t owns l = 4t..4t+3.
// x_l = Re(w a^l); one polar eval (mag, sin, cos at l0=4t) seeds all 4
// elements via precomputed w*a^k, k=0..3:
//   (x_{l0+j}) = wr_j*mc - wi_j*ms,  packed in pairs.
__global__ __launch_bounds__(NT, 8)
void lssl_kernel(const float* __restrict__ Lre, const float* __restrict__ Lim,
                 const float* __restrict__ Bre, const float* __restrict__ Bim,
                 const float* __restrict__ Cre, const float* __restrict__ Cim,
                 const float* __restrict__ Dv,  const float* __restrict__ log_dt,
                 float* __restrict__ out)
{
    const int h = blockIdx.x;
    const int t = threadIdx.x;

    __shared__ f32x4 sA[N_DIM];   // (wr0, wr1, wi0, wi1)  : w, w*a
    __shared__ f32x4 sB[N_DIM];   // (wr2, wr3, wi2, wi3)  : w*a^2, w*a^3
    __shared__ f32x2 sPL[N_DIM];  // (log2|a|, arg(a)/2pi)

    if (t < N_DIM) {
        const int   idx = h * N_DIM + t;
        const float dt  = expf(log_dt[h]);
        const float lre = Lre[idx];
        const float lim = Lim[idx];
        const float sp  = log1pf(expf(lre));     // softplus
        const float hr  = -0.5f * dt * sp;
        const float hi  =  0.5f * dt * lim;
        const float dr  = 1.0f - hr;             // denom = (dr, -hi)
        const float inv = 1.0f / (dr * dr + hi * hi);
        const float xr  = 1.0f + hr;
        const float ar  = (xr * dr - hi * hi) * inv;   // a_bar
        const float ai  = 2.0f * hi * inv;
        const float tr  = dt * dr * inv;
        const float ti  = dt * hi * inv;
        const float bre = Bre[idx], bim = Bim[idx];
        const float br  = tr * bre - ti * bim;         // b_bar
        const float bi  = tr * bim + ti * bre;
        const float cre = Cre[idx], cim = Cim[idx];
        const float wr0 = cre * br - cim * bi;         // w = C*b_bar
        const float wi0 = cre * bi + cim * br;
        const float wr1 = wr0 * ar - wi0 * ai;         // w*a
        const float wi1 = wr0 * ai + wi0 * ar;
        const float wr2 = wr1 * ar - wi1 * ai;         // w*a^2
        const float wi2 = wr1 * ai + wi1 * ar;
        const float wr3 = wr2 * ar - wi2 * ai;         // w*a^3
        const float wi3 = wr2 * ai + wi2 * ar;

        const float m2   = ar * ar + ai * ai;
        const float lg2A = 0.5f * log2f(m2);
        const float thRv = atan2f(ai, ar) * 0.15915494309189535f;

        sA[t]  = (f32x4){wr0, wr1, wi0, wi1};
        sB[t]  = (f32x4){wr2, wr3, wi2, wi3};
        sPL[t] = (f32x2){lg2A, thRv};
    }
    __syncthreads();

    const float l0f = (float)(t * CHUNK);
    f32x2 acc0 = {0.f, 0.f}, acc1 = {0.f, 0.f};

#pragma unroll 2
    for (int n = 0; n < N_DIM; ++n) {
        const f32x2 pl  = sPL[n];
        const float mag = exp2_hw(l0f * pl[0]);
        const float rv  = fract_hw(l0f * pl[1]);
        const float s   = sin_rev(rv);
        const float c   = cos_rev(rv);
        f32x2 mcms;
        mcms[0] = mag * c;
        mcms[1] = mag * s;

        const f32x4 a4 = sA[n], b4 = sB[n];
        const f32x2 WR01 = {a4[0], a4[1]}, WI01 = {a4[2], a4[3]};
        const f32x2 WR23 = {b4[0], b4[1]}, WI23 = {b4[2], b4[3]};

        const f32x2 y0 = pk_fms_blo(WR01, mcms, pk_mul_bhi(WI01, mcms)); // (x0,x1)
        const f32x2 y1 = pk_fms_blo(WR23, mcms, pk_mul_bhi(WI23, mcms)); // (x2,x3)
        acc0 = pk_add(acc0, y0);
        acc1 = pk_add(acc1, y1);
    }

    float* orow = out + (size_t)h * L_DIM + (size_t)t * CHUNK;
    *reinterpret_cast<float4*>(orow) =
        make_float4(acc0[0], acc0[1], acc1[0], acc1[1]);

    if (t == 0) out[(size_t)H_DIM * L_DIM + h] = Dv[h];
}

extern "C" void kernel_launch(void* const* d_in, const int* in_sizes, int n_in,
                              void* d_out, int out_size, void* d_ws, size_t ws_size,
                              hipStream_t stream) {
    const float* Lre   = (const float*)d_in[0];
    const float* Lim   = (const float*)d_in[1];
    const float* Bre   = (const float*)d_in[2];
    const float* Bim   = (const float*)d_in[3];
    const float* Cre   = (const float*)d_in[4];
    const float* Cim   = (const float*)d_in[5];
    const float* Dv    = (const float*)d_in[6];
    const float* logdt = (const float*)d_in[7];
    float* out = (float*)d_out;

    lssl_kernel<<<dim3(H_DIM), dim3(NT), 0, stream>>>(
        Lre, Lim, Bre, Bim, Cre, Cim, Dv, logdt, out);
}

// Round 6
// 11.585 us; speedup vs baseline: 2.0637x; 2.0637x over previous
//
#include <hip/hip_runtime.h>
#include <math.h>

#define H_DIM 1024
#define N_DIM 64
#define L_DIM 2048
#define NT 256
#define SA 72   // A row stride (bf16 elems): 64 + 8 pad
#define SB 40   // B row stride: 32 + 8 pad

typedef float  f32x4  __attribute__((ext_vector_type(4)));
typedef short  bf16x8 __attribute__((ext_vector_type(8)));

__device__ __forceinline__ short f2bf(float x) {
    unsigned u = __builtin_bit_cast(unsigned, x);
    u += 0x7FFFu + ((u >> 16) & 1u);          // round-nearest-even
    return (short)(u >> 16);
}
__device__ __forceinline__ float2 cmul(float2 x, float2 y) {
    return make_float2(fmaf(x.x, y.x, -(x.y * y.y)),
                       fmaf(x.x, y.y,  x.y * y.x));
}
__device__ __forceinline__ float2 csq(float2 x) {
    return make_float2(fmaf(x.x, x.x, -(x.y * x.y)), 2.0f * x.x * x.y);
}

// K[h][32*l1 + l0] = sum_n ( Re(U)[n][l1]*Re(V)[n][l0] - Im(U)[n][l1]*Im(V)[n][l0] )
//   U[n][l1] = w_n * (a_n^32)^l1   (A matrix, M=64 rows l1, K=64 cols n)
//   V[n][l0] = a_n^l0              (B matrix, K=64 rows n, N=32 cols l0)
// One block per h: 256 threads = (n, q); lane-n chains generate U,V in bf16 LDS
// (no transcendentals), then wave q MFMAs M-tile q. A_im stored negated.
__global__ __launch_bounds__(NT, 4)
void lssl_mfma(const float* __restrict__ Lre, const float* __restrict__ Lim,
               const float* __restrict__ Bre, const float* __restrict__ Bim,
               const float* __restrict__ Cre, const float* __restrict__ Cim,
               const float* __restrict__ Dv,  const float* __restrict__ log_dt,
               float* __restrict__ out)
{
    __shared__ __align__(16) short sAre[64 * SA];  // [l1][n]
    __shared__ __align__(16) short sAim[64 * SA];  // negated Im(U)
    __shared__ __align__(16) short sBre[64 * SB];  // [n][l0]
    __shared__ __align__(16) short sBim[64 * SB];

    const int h = blockIdx.x;
    const int t = threadIdx.x;
    const int n = t & 63;
    const int q = t >> 6;          // 0..3, wave-uniform

    // ---- per-(h,n) params (same verified math as prior rounds) ----
    const int   idx = h * N_DIM + n;
    const float dt  = expf(log_dt[h]);
    const float lre = Lre[idx];
    const float lim = Lim[idx];
    const float sp  = log1pf(expf(lre));     // softplus
    const float hr  = -0.5f * dt * sp;
    const float hi  =  0.5f * dt * lim;
    const float dr  = 1.0f - hr;             // denom = (dr, -hi)
    const float inv = 1.0f / (dr * dr + hi * hi);
    const float xr  = 1.0f + hr;
    float2 a  = make_float2((xr * dr - hi * hi) * inv, 2.0f * hi * inv); // a_bar
    const float tr  = dt * dr * inv;
    const float ti  = dt * hi * inv;
    const float br  = tr * Bre[idx] - ti * Bim[idx];   // b_bar
    const float bi  = tr * Bim[idx] + ti * Bre[idx];
    const float cre = Cre[idx], cim = Cim[idx];
    float2 w  = make_float2(cre * br - cim * bi,       // w = C*b_bar
                            cre * bi + cim * br);

    // ---- powers by squaring ----
    const float2 a2   = csq(a);
    const float2 a4   = csq(a2);
    const float2 a8   = csq(a4);
    const float2 a16  = csq(a8);
    const float2 a32  = csq(a16);
    const float2 a64  = csq(a32);
    const float2 a128 = csq(a64);
    const float2 a256 = csq(a128);
    const float2 a512 = csq(a256);

    // ---- U chain: l1 = 16q..16q+15, U = w * a^(32*l1) ----
    float2 s = w;
    for (int k = 0; k < q; ++k) s = cmul(s, a512);   // w * a^(512q)
#pragma unroll
    for (int j = 0; j < 16; ++j) {
        const int l1 = 16 * q + j;
        sAre[l1 * SA + n] = f2bf(s.x);
        sAim[l1 * SA + n] = f2bf(-s.y);
        s = cmul(s, a32);
    }

    // ---- V chain: l0 = 8q..8q+7, V = a^l0 ----
    float2 v = make_float2(1.0f, 0.0f);
    for (int k = 0; k < q; ++k) v = cmul(v, a8);     // a^(8q)
#pragma unroll
    for (int i = 0; i < 8; ++i) {
        sBre[n * SB + 8 * q + i] = f2bf(v.x);
        sBim[n * SB + 8 * q + i] = f2bf(v.y);
        v = cmul(v, a);
    }

    __syncthreads();

    // ---- MFMA: wave q owns M-tile q (l1 rows 16q..16q+15) ----
    const int col = t & 15;
    const int grp = (t & 63) >> 4;
    f32x4 acc0 = {0.f, 0.f, 0.f, 0.f};
    f32x4 acc1 = {0.f, 0.f, 0.f, 0.f};

#pragma unroll
    for (int kt = 0; kt < 2; ++kt) {
        const int kbase = kt * 32 + grp * 8;          // k-hat bijection: 8g+j
        const bf16x8 afr = *(const bf16x8*)&sAre[(q * 16 + col) * SA + kbase];
        const bf16x8 afi = *(const bf16x8*)&sAim[(q * 16 + col) * SA + kbase];
        bf16x8 b0r, b0i, b1r, b1i;
#pragma unroll
        for (int j = 0; j < 8; ++j) {
            const int r = (kbase + j) * SB + col;
            b0r[j] = sBre[r];       b0i[j] = sBim[r];
            b1r[j] = sBre[r + 16];  b1i[j] = sBim[r + 16];
        }
        acc0 = __builtin_amdgcn_mfma_f32_16x16x32_bf16(afr, b0r, acc0, 0, 0, 0);
        acc0 = __builtin_amdgcn_mfma_f32_16x16x32_bf16(afi, b0i, acc0, 0, 0, 0);
        acc1 = __builtin_amdgcn_mfma_f32_16x16x32_bf16(afr, b1r, acc1, 0, 0, 0);
        acc1 = __builtin_amdgcn_mfma_f32_16x16x32_bf16(afi, b1i, acc1, 0, 0, 0);
    }

    // ---- store: D row=(lane>>4)*4+reg, col=lane&15 (measured C/D layout) ----
    float* o = out + (size_t)h * L_DIM;
#pragma unroll
    for (int r = 0; r < 4; ++r) {
        const int row = q * 16 + grp * 4 + r;         // l1
        o[row * 32 + col]      = acc0[r];
        o[row * 32 + 16 + col] = acc1[r];
    }

    if (t == 0) out[(size_t)H_DIM * L_DIM + h] = Dv[h];
}

extern "C" void kernel_launch(void* const* d_in, const int* in_sizes, int n_in,
                              void* d_out, int out_size, void* d_ws, size_t ws_size,
                              hipStream_t stream) {
    const float* Lre   = (const float*)d_in[0];
    const float* Lim   = (const float*)d_in[1];
    const float* Bre   = (const float*)d_in[2];
    const float* Bim   = (const float*)d_in[3];
    const float* Cre   = (const float*)d_in[4];
    const float* Cim   = (const float*)d_in[5];
    const float* Dv    = (const float*)d_in[6];
    const float* logdt = (const float*)d_in[7];
    float* out = (float*)d_out;

    lssl_mfma<<<dim3(H_DIM), dim3(NT), 0, stream>>>(
        Lre, Lim, Bre, Bim, Cre, Cim, Dv, logdt, out);
}